// Round 4
// baseline (418.849 us; speedup 1.0000x reference)
//
#include <hip/hip_runtime.h>

#define N_NODES 50000
#define N_EDGES 800000
#define IN_DIM  128
#define HID_DIM 256
#define OUT_DIM 128
#define BUCKET_CAP 64    // in-degree ~ Poisson(16); P(deg>64) ~ 2e-18 over 50k nodes
#define NBINS 782        // ceil(50000/64) bins of 64 dst nodes each
#define BIN_CAP 1536     // Poisson(1024) + 16 sigma

typedef __attribute__((ext_vector_type(8))) short short8;
typedef __attribute__((ext_vector_type(4))) float f32x4;

// ---- bf16 helpers (RNE) ----
__device__ inline ushort f2b(float f) {
    union { float f; unsigned u; } v; v.f = f;
    return (ushort)((v.u + 0x7FFFu + ((v.u >> 16) & 1u)) >> 16);
}
__device__ inline float b2f(ushort h) {
    union { unsigned u; float f; } v; v.u = ((unsigned)h) << 16;
    return v.f;
}
__device__ inline float2 u2f2(unsigned u) {
    float2 r; r.x = b2f((ushort)(u & 0xFFFFu)); r.y = b2f((ushort)(u >> 16)); return r;
}
__device__ inline void fma2(float2& a, const float2 v, float n) {
    a.x += v.x * n; a.y += v.y * n;
}

// ---------------- graph build: two-phase binned bucket fill ----------------

__global__ void zero_bins_kernel(int* __restrict__ p) {
    int i = blockIdx.x * blockDim.x + threadIdx.x;
    if (i < NBINS) p[i] = 0;
}

// pass 1: bin edges by dst>>6; sequential append within bin => coalesced-ish lines
__global__ __launch_bounds__(256) void binpass1_kernel(const int* __restrict__ src,
                                                       const int* __restrict__ dst,
                                                       int* __restrict__ bincnt,
                                                       int* __restrict__ binbuf) {
    int e = blockIdx.x * blockDim.x + threadIdx.x;
    if (e >= N_EDGES) return;
    int s = src[e], d = dst[e];
    int bin = d >> 6;
    int pos = atomicAdd(&bincnt[bin], 1);
    if (pos < BIN_CAP) binbuf[bin * BIN_CAP + pos] = (s << 6) | (d & 63);
}

// pass 2: one block per bin; build 64-node bucket region in LDS, write coalesced.
// Also emits cnt + dinv (folds the old dinv_kernel).
__global__ __launch_bounds__(256) void binpass2_kernel(const int* __restrict__ bincnt,
                                                       const int* __restrict__ binbuf,
                                                       int* __restrict__ cnt,
                                                       float* __restrict__ dinv,
                                                       int* __restrict__ bucket) {
    __shared__ int lcnt[64];
    __shared__ int lbuck[64 * BUCKET_CAP];   // 16 KB
    const int bin = blockIdx.x;
    const int t = threadIdx.x;
    if (t < 64) lcnt[t] = 0;
    __syncthreads();
    int m = bincnt[bin];
    if (m > BIN_CAP) m = BIN_CAP;
    const int* bb = binbuf + (size_t)bin * BIN_CAP;
    for (int j = t; j < m; j += 256) {
        int v = bb[j];
        int dl = v & 63;
        int pos = atomicAdd(&lcnt[dl], 1);
        if (pos < BUCKET_CAP) lbuck[dl * BUCKET_CAP + pos] = v >> 6;
    }
    __syncthreads();
    const int node0 = bin * 64;
    if (t < 64) {
        int node = node0 + t;
        if (node < N_NODES) {
            int c = lcnt[t] > BUCKET_CAP ? BUCKET_CAP : lcnt[t];
            cnt[node] = c;
            dinv[node] = rsqrtf((float)c + 1.0f);
        }
    }
    int nvalid = N_NODES - node0; if (nvalid > 64) nvalid = 64;
    int total4 = (nvalid * BUCKET_CAP) >> 2;     // int4 count
    int4* d4 = (int4*)(bucket + (size_t)node0 * BUCKET_CAP);
    const int4* s4 = (const int4*)lbuck;
    for (int j = t; j < total4; j += 256) d4[j] = s4[j];
}

// ---------------- fp32 -> bf16 conversions ----------------

__global__ void conv_x_kernel(const float* __restrict__ x, ushort* __restrict__ xb) {
    int i = blockIdx.x * blockDim.x + threadIdx.x;  // over 6.4M/4
    float4 v = ((const float4*)x)[i];
    ushort4 o; o.x = f2b(v.x); o.y = f2b(v.y); o.z = f2b(v.z); o.w = f2b(v.w);
    ((ushort4*)xb)[i] = o;
}

// W1 [128x256] -> w1t [256x128] (bf16, transposed); W2 [256x128] -> w2t [128x256]
__global__ void conv_w_kernel(const float* __restrict__ W1, const float* __restrict__ W2,
                              ushort* __restrict__ w1t, ushort* __restrict__ w2t) {
    int i = blockIdx.x * blockDim.x + threadIdx.x;  // 65536 total
    if (i < 32768) {
        int n = i >> 7, k = i & 127;
        w1t[i] = f2b(W1[k * HID_DIM + n]);
    } else {
        int j = i - 32768;
        int n = j >> 8, k = j & 255;
        w2t[j] = f2b(W2[k * OUT_DIM + n]);
    }
}

// ---------------- gather0: aggx = Ahat * x (bf16 in/out, fp32 acc) ----------------
// one wave per dst node; branch-free unroll-8 (pad lanes: sv=0, nv=0)

__global__ __launch_bounds__(256) void gather0_kernel(const int* __restrict__ cnt,
                                                      const int* __restrict__ bucket,
                                                      const float* __restrict__ dinv,
                                                      const ushort* __restrict__ xb,
                                                      ushort* __restrict__ aggxb) {
    const int w = blockIdx.x * 4 + (threadIdx.x >> 6);
    const int lane = threadIdx.x & 63;
    const int n = cnt[w];
    const float dd = dinv[w];
    int sv = 0; float nv = 0.f;
    if (lane < n) { sv = bucket[w * BUCKET_CAP + lane]; nv = dinv[sv] * dd; }

    float2 self = u2f2(((const unsigned*)(xb + (size_t)w * IN_DIM))[lane]);
    float sd = dd * dd;
    float2 acc[8];
    acc[0] = {self.x * sd, self.y * sd};
#pragma unroll
    for (int j = 1; j < 8; ++j) acc[j] = {0.f, 0.f};

    const int nr = (n + 7) & ~7;
    for (int i = 0; i < nr; i += 8) {
        int s[8]; float nm[8]; unsigned u[8];
#pragma unroll
        for (int j = 0; j < 8; ++j) { s[j] = __shfl(sv, i + j); nm[j] = __shfl(nv, i + j); }
#pragma unroll
        for (int j = 0; j < 8; ++j) u[j] = ((const unsigned*)(xb + (size_t)s[j] * IN_DIM))[lane];
#pragma unroll
        for (int j = 0; j < 8; ++j) fma2(acc[j], u2f2(u[j]), nm[j]);
    }
#pragma unroll
    for (int j = 1; j < 8; ++j) { acc[0].x += acc[j].x; acc[0].y += acc[j].y; }
    unsigned o = (unsigned)f2b(acc[0].x) | ((unsigned)f2b(acc[0].y) << 16);
    ((unsigned*)(aggxb + (size_t)w * IN_DIM))[lane] = o;
}

// ---------------- gemm1 (MFMA): Hb = relu(aggx @ W1 + b1), bf16 out ----------------

__global__ __launch_bounds__(256) void gemm1_mfma(const ushort* __restrict__ aggxb,
                                                  const ushort* __restrict__ w1t,
                                                  const float* __restrict__ b1,
                                                  ushort* __restrict__ Hb) {
    const int row0 = blockIdx.x * 16;
    const int wv = threadIdx.x >> 6;
    const int lane = threadIdx.x & 63;
    const int l15 = lane & 15, q = lane >> 4;
    f32x4 acc[4] = {{0.f, 0.f, 0.f, 0.f}, {0.f, 0.f, 0.f, 0.f},
                    {0.f, 0.f, 0.f, 0.f}, {0.f, 0.f, 0.f, 0.f}};
    const ushort* abase = aggxb + (size_t)(row0 + l15) * IN_DIM + q * 8;
#pragma unroll
    for (int kb = 0; kb < 4; ++kb) {
        short8 a = *(const short8*)(abase + kb * 32);
#pragma unroll
        for (int t = 0; t < 4; ++t) {
            int col = wv * 64 + t * 16 + l15;
            short8 b = *(const short8*)(w1t + (size_t)col * IN_DIM + kb * 32 + q * 8);
            acc[t] = __builtin_amdgcn_mfma_f32_16x16x32_bf16(a, b, acc[t], 0, 0, 0);
        }
    }
#pragma unroll
    for (int t = 0; t < 4; ++t) {
        int col = wv * 64 + t * 16 + l15;
        float bias = b1[col];
#pragma unroll
        for (int r = 0; r < 4; ++r) {
            int row = row0 + q * 4 + r;
            float v = acc[t][r] + bias;
            Hb[(size_t)row * HID_DIM + col] = f2b(v > 0.f ? v : 0.f);
        }
    }
}

// ---------------- gemm2 (MFMA): h2b = Hb @ W2, bf16 out ----------------

__global__ __launch_bounds__(256) void gemm2_mfma(const ushort* __restrict__ Hb,
                                                  const ushort* __restrict__ w2t,
                                                  ushort* __restrict__ h2b) {
    const int row0 = blockIdx.x * 16;
    const int wv = threadIdx.x >> 6;
    const int lane = threadIdx.x & 63;
    const int l15 = lane & 15, q = lane >> 4;
    f32x4 acc[2] = {{0.f, 0.f, 0.f, 0.f}, {0.f, 0.f, 0.f, 0.f}};
    const ushort* abase = Hb + (size_t)(row0 + l15) * HID_DIM + q * 8;
#pragma unroll
    for (int kb = 0; kb < 8; ++kb) {
        short8 a = *(const short8*)(abase + kb * 32);
#pragma unroll
        for (int t = 0; t < 2; ++t) {
            int col = wv * 32 + t * 16 + l15;
            short8 b = *(const short8*)(w2t + (size_t)col * HID_DIM + kb * 32 + q * 8);
            acc[t] = __builtin_amdgcn_mfma_f32_16x16x32_bf16(a, b, acc[t], 0, 0, 0);
        }
    }
#pragma unroll
    for (int t = 0; t < 2; ++t) {
        int col = wv * 32 + t * 16 + l15;
#pragma unroll
        for (int r = 0; r < 4; ++r) {
            int row = row0 + q * 4 + r;
            h2b[(size_t)row * OUT_DIM + col] = f2b(acc[t][r]);
        }
    }
}

// ---------------- gather2: out = Ahat * h2 + b2 (bf16 in, fp32 out) ----------------

__global__ __launch_bounds__(256) void gather2_kernel(const int* __restrict__ cnt,
                                                      const int* __restrict__ bucket,
                                                      const float* __restrict__ dinv,
                                                      const ushort* __restrict__ h2b,
                                                      const float* __restrict__ b2,
                                                      float* __restrict__ out) {
    const int w = blockIdx.x * 4 + (threadIdx.x >> 6);
    const int lane = threadIdx.x & 63;
    const int n = cnt[w];
    const float dd = dinv[w];
    int sv = 0; float nv = 0.f;
    if (lane < n) { sv = bucket[w * BUCKET_CAP + lane]; nv = dinv[sv] * dd; }

    float2 bb = ((const float2*)b2)[lane];
    float2 self = u2f2(((const unsigned*)(h2b + (size_t)w * OUT_DIM))[lane]);
    float sd = dd * dd;
    float2 acc[8];
    acc[0] = {self.x * sd + bb.x, self.y * sd + bb.y};
#pragma unroll
    for (int j = 1; j < 8; ++j) acc[j] = {0.f, 0.f};

    const int nr = (n + 7) & ~7;
    for (int i = 0; i < nr; i += 8) {
        int s[8]; float nm[8]; unsigned u[8];
#pragma unroll
        for (int j = 0; j < 8; ++j) { s[j] = __shfl(sv, i + j); nm[j] = __shfl(nv, i + j); }
#pragma unroll
        for (int j = 0; j < 8; ++j) u[j] = ((const unsigned*)(h2b + (size_t)s[j] * OUT_DIM))[lane];
#pragma unroll
        for (int j = 0; j < 8; ++j) fma2(acc[j], u2f2(u[j]), nm[j]);
    }
#pragma unroll
    for (int j = 1; j < 8; ++j) { acc[0].x += acc[j].x; acc[0].y += acc[j].y; }
    ((float2*)(out + (size_t)w * OUT_DIM))[lane] = acc[0];
}

extern "C" void kernel_launch(void* const* d_in, const int* in_sizes, int n_in,
                              void* d_out, int out_size, void* d_ws, size_t ws_size,
                              hipStream_t stream) {
    const float* x  = (const float*)d_in[0];
    const int*   ei = (const int*)d_in[1];
    const float* W1 = (const float*)d_in[2];
    const float* b1 = (const float*)d_in[3];
    const float* W2 = (const float*)d_in[4];
    const float* b2 = (const float*)d_in[5];
    float* out = (float*)d_out;

    const int* src = ei;             // edge_index[0]
    const int* dst = ei + N_EDGES;   // edge_index[1]

    // workspace layout (bytes):
    //  bincnt : [0, 4096)                   int[782]
    //  cnt    : [4096, 204096)              int[50000]
    //  dinv   : [204096, 404096)            float[50000]
    //  bucket : [404096, 13204096)          int[50000*64]
    //  binbuf : [13204096, 18008704)        int[782*1536]
    //  xb     : [18008704, 30808704)        bf16[50000*128]
    //  aggxb  : [30808704, 43608704)        bf16[50000*128]
    //  w1t    : [43608704, 43674240)        bf16[256*128]
    //  w2t    : [43674240, 43739776)        bf16[128*256]
    //  Hb     : [43739776, 69339776)        bf16[50000*256]
    //  h2b    : [69339776, 82139776)        bf16[50000*128]
    char* ws = (char*)d_ws;
    int*    bincnt = (int*)(ws);
    int*    cnt    = (int*)(ws + 4096);
    float*  dinv   = (float*)(ws + 204096);
    int*    bucket = (int*)(ws + 404096);
    int*    binbuf = (int*)(ws + 13204096);
    ushort* xb     = (ushort*)(ws + 18008704);
    ushort* aggxb  = (ushort*)(ws + 30808704);
    ushort* w1t    = (ushort*)(ws + 43608704);
    ushort* w2t    = (ushort*)(ws + 43674240);
    ushort* Hb     = (ushort*)(ws + 43739776);
    ushort* h2b    = (ushort*)(ws + 69339776);

    // graph build (two-phase binned) + dtype prep
    zero_bins_kernel<<<(NBINS + 255) / 256, 256, 0, stream>>>(bincnt);
    binpass1_kernel<<<N_EDGES / 256, 256, 0, stream>>>(src, dst, bincnt, binbuf);
    binpass2_kernel<<<NBINS, 256, 0, stream>>>(bincnt, binbuf, cnt, dinv, bucket);
    conv_x_kernel<<<(N_NODES * IN_DIM / 4) / 256, 256, 0, stream>>>(x, xb);
    conv_w_kernel<<<65536 / 256, 256, 0, stream>>>(W1, W2, w1t, w2t);

    // layer 1 reordered: aggregate x first, then transform (relu+b1 fused in epilogue)
    gather0_kernel<<<N_NODES / 4, 256, 0, stream>>>(cnt, bucket, dinv, xb, aggxb);
    gemm1_mfma<<<N_NODES / 16, 256, 0, stream>>>(aggxb, w1t, b1, Hb);

    // layer 2: transform then aggregate (self-loop + b2 fused into gather2)
    gemm2_mfma<<<N_NODES / 16, 256, 0, stream>>>(Hb, w2t, h2b);
    gather2_kernel<<<N_NODES / 4, 256, 0, stream>>>(cnt, bucket, dinv, h2b, b2, out);
}

// Round 5
// 270.996 us; speedup vs baseline: 1.5456x; 1.5456x over previous
//
#include <hip/hip_runtime.h>

#define N_NODES 50000
#define N_EDGES 800000
#define IN_DIM  128
#define HID_DIM 256
#define OUT_DIM 128
#define BUCKET_CAP 64    // in-degree ~ Poisson(16); P(deg>64) ~ 2e-18 over 50k nodes
#define NBINS 782        // ceil(50000/64) bins of 64 dst nodes each
#define NSUB 32          // sub-buffers per bin (contention: ~32 contenders/counter)
#define SUBCAP 96        // Poisson(32) + 11 sigma per (bin,sub)

typedef __attribute__((ext_vector_type(8))) short short8;
typedef __attribute__((ext_vector_type(4))) float f32x4;

// ---- bf16 helpers (RNE) ----
__device__ inline ushort f2b(float f) {
    union { float f; unsigned u; } v; v.f = f;
    return (ushort)((v.u + 0x7FFFu + ((v.u >> 16) & 1u)) >> 16);
}
__device__ inline float b2f(ushort h) {
    union { unsigned u; float f; } v; v.u = ((unsigned)h) << 16;
    return v.f;
}
__device__ inline float2 u2f2(unsigned u) {
    float2 r; r.x = b2f((ushort)(u & 0xFFFFu)); r.y = b2f((ushort)(u >> 16)); return r;
}
__device__ inline void fma2(float2& a, const float2 v, float n) {
    a.x += v.x * n; a.y += v.y * n;
}

// ---------------- fp32 -> bf16 conversion (+ zero bincnt2, fused) ----------------

__global__ void conv_x_kernel(const float* __restrict__ x, ushort* __restrict__ xb,
                              int* __restrict__ bincnt2) {
    int i = blockIdx.x * blockDim.x + threadIdx.x;  // 1.6M threads
    if (i < NBINS * NSUB) bincnt2[i] = 0;
    float4 v = ((const float4*)x)[i];
    ushort4 o; o.x = f2b(v.x); o.y = f2b(v.y); o.z = f2b(v.z); o.w = f2b(v.w);
    ((ushort4*)xb)[i] = o;
}

// W1 [128x256] -> w1t [256x128] (bf16, transposed); W2 [256x128] -> w2t [128x256]
__global__ void conv_w_kernel(const float* __restrict__ W1, const float* __restrict__ W2,
                              ushort* __restrict__ w1t, ushort* __restrict__ w2t) {
    int i = blockIdx.x * blockDim.x + threadIdx.x;  // 65536 total
    if (i < 32768) {
        int n = i >> 7, k = i & 127;
        w1t[i] = f2b(W1[k * HID_DIM + n]);
    } else {
        int j = i - 32768;
        int n = j >> 8, k = j & 255;
        w2t[j] = f2b(W2[k * OUT_DIM + n]);
    }
}

// ---------------- graph build: two-phase binned bucket fill ----------------
// pass 1: bin edges by dst>>6, 32 sub-buffers per bin keyed by blockIdx&31
// => ~32-way atomic contention (vs 1024-way in the failed single-counter version)

__global__ __launch_bounds__(256) void binpass1_kernel(const int* __restrict__ src,
                                                       const int* __restrict__ dst,
                                                       int* __restrict__ bincnt2,
                                                       int* __restrict__ binbuf) {
    int e = blockIdx.x * blockDim.x + threadIdx.x;
    int s = src[e], d = dst[e];
    int bin = d >> 6;
    int g = blockIdx.x & (NSUB - 1);
    int idx = bin * NSUB + g;
    int pos = atomicAdd(&bincnt2[idx], 1);
    if (pos < SUBCAP) binbuf[(size_t)idx * SUBCAP + pos] = (s << 6) | (d & 63);
}

// pass 2: one block per bin; merge 32 segments into 64-node bucket region via LDS,
// write bucket + cnt + dinv coalesced.
__global__ __launch_bounds__(256) void binpass2_kernel(const int* __restrict__ bincnt2,
                                                       const int* __restrict__ binbuf,
                                                       int* __restrict__ cnt,
                                                       float* __restrict__ dinv,
                                                       int* __restrict__ bucket) {
    __shared__ int lcnt[64];
    __shared__ int mcnt[NSUB];
    __shared__ int lbuck[64 * BUCKET_CAP];   // 16 KB
    const int bin = blockIdx.x;
    const int t = threadIdx.x;
    if (t < 64) lcnt[t] = 0;
    if (t < NSUB) {
        int m = bincnt2[bin * NSUB + t];
        mcnt[t] = m > SUBCAP ? SUBCAP : m;
    }
    __syncthreads();
    const int* bb = binbuf + (size_t)bin * NSUB * SUBCAP;
    for (int f = t; f < NSUB * SUBCAP; f += 256) {
        int g = f / SUBCAP;
        int j = f - g * SUBCAP;
        if (j < mcnt[g]) {
            int v = bb[f];
            int dl = v & 63;
            int pos = atomicAdd(&lcnt[dl], 1);
            if (pos < BUCKET_CAP) lbuck[dl * BUCKET_CAP + pos] = v >> 6;
        }
    }
    __syncthreads();
    const int node0 = bin * 64;
    if (t < 64) {
        int node = node0 + t;
        if (node < N_NODES) {
            int c = lcnt[t] > BUCKET_CAP ? BUCKET_CAP : lcnt[t];
            cnt[node] = c;
            dinv[node] = rsqrtf((float)c + 1.0f);
        }
    }
    int nvalid = N_NODES - node0; if (nvalid > 64) nvalid = 64;
    if (nvalid <= 0) return;
    int total4 = (nvalid * BUCKET_CAP) >> 2;     // int4 count
    int4* d4 = (int4*)(bucket + (size_t)node0 * BUCKET_CAP);
    const int4* s4 = (const int4*)lbuck;
    for (int j = t; j < total4; j += 256) d4[j] = s4[j];
}

// ---------------- gather0: aggx = Ahat * x (bf16 in/out, fp32 acc) ----------------
// one wave per dst node; branch-free unroll-8 (pad lanes: sv=0, nv=0)

__global__ __launch_bounds__(256) void gather0_kernel(const int* __restrict__ cnt,
                                                      const int* __restrict__ bucket,
                                                      const float* __restrict__ dinv,
                                                      const ushort* __restrict__ xb,
                                                      ushort* __restrict__ aggxb) {
    const int w = blockIdx.x * 4 + (threadIdx.x >> 6);
    const int lane = threadIdx.x & 63;
    const int n = cnt[w];
    const float dd = dinv[w];
    int sv = 0; float nv = 0.f;
    if (lane < n) { sv = bucket[w * BUCKET_CAP + lane]; nv = dinv[sv] * dd; }

    float2 self = u2f2(((const unsigned*)(xb + (size_t)w * IN_DIM))[lane]);
    float sd = dd * dd;
    float2 acc[8];
    acc[0] = {self.x * sd, self.y * sd};
#pragma unroll
    for (int j = 1; j < 8; ++j) acc[j] = {0.f, 0.f};

    const int nr = (n + 7) & ~7;
    for (int i = 0; i < nr; i += 8) {
        int s[8]; float nm[8]; unsigned u[8];
#pragma unroll
        for (int j = 0; j < 8; ++j) { s[j] = __shfl(sv, i + j); nm[j] = __shfl(nv, i + j); }
#pragma unroll
        for (int j = 0; j < 8; ++j) u[j] = ((const unsigned*)(xb + (size_t)s[j] * IN_DIM))[lane];
#pragma unroll
        for (int j = 0; j < 8; ++j) fma2(acc[j], u2f2(u[j]), nm[j]);
    }
#pragma unroll
    for (int j = 1; j < 8; ++j) { acc[0].x += acc[j].x; acc[0].y += acc[j].y; }
    unsigned o = (unsigned)f2b(acc[0].x) | ((unsigned)f2b(acc[0].y) << 16);
    ((unsigned*)(aggxb + (size_t)w * IN_DIM))[lane] = o;
}

// ---------------- gemm1 (MFMA): Hb = relu(aggx @ W1 + b1), bf16 out ----------------

__global__ __launch_bounds__(256) void gemm1_mfma(const ushort* __restrict__ aggxb,
                                                  const ushort* __restrict__ w1t,
                                                  const float* __restrict__ b1,
                                                  ushort* __restrict__ Hb) {
    const int row0 = blockIdx.x * 16;
    const int wv = threadIdx.x >> 6;
    const int lane = threadIdx.x & 63;
    const int l15 = lane & 15, q = lane >> 4;
    f32x4 acc[4] = {{0.f, 0.f, 0.f, 0.f}, {0.f, 0.f, 0.f, 0.f},
                    {0.f, 0.f, 0.f, 0.f}, {0.f, 0.f, 0.f, 0.f}};
    const ushort* abase = aggxb + (size_t)(row0 + l15) * IN_DIM + q * 8;
#pragma unroll
    for (int kb = 0; kb < 4; ++kb) {
        short8 a = *(const short8*)(abase + kb * 32);
#pragma unroll
        for (int t = 0; t < 4; ++t) {
            int col = wv * 64 + t * 16 + l15;
            short8 b = *(const short8*)(w1t + (size_t)col * IN_DIM + kb * 32 + q * 8);
            acc[t] = __builtin_amdgcn_mfma_f32_16x16x32_bf16(a, b, acc[t], 0, 0, 0);
        }
    }
#pragma unroll
    for (int t = 0; t < 4; ++t) {
        int col = wv * 64 + t * 16 + l15;
        float bias = b1[col];
#pragma unroll
        for (int r = 0; r < 4; ++r) {
            int row = row0 + q * 4 + r;
            float v = acc[t][r] + bias;
            Hb[(size_t)row * HID_DIM + col] = f2b(v > 0.f ? v : 0.f);
        }
    }
}

// ---------------- gemm2 (MFMA): h2b = Hb @ W2, bf16 out ----------------

__global__ __launch_bounds__(256) void gemm2_mfma(const ushort* __restrict__ Hb,
                                                  const ushort* __restrict__ w2t,
                                                  ushort* __restrict__ h2b) {
    const int row0 = blockIdx.x * 16;
    const int wv = threadIdx.x >> 6;
    const int lane = threadIdx.x & 63;
    const int l15 = lane & 15, q = lane >> 4;
    f32x4 acc[2] = {{0.f, 0.f, 0.f, 0.f}, {0.f, 0.f, 0.f, 0.f}};
    const ushort* abase = Hb + (size_t)(row0 + l15) * HID_DIM + q * 8;
#pragma unroll
    for (int kb = 0; kb < 8; ++kb) {
        short8 a = *(const short8*)(abase + kb * 32);
#pragma unroll
        for (int t = 0; t < 2; ++t) {
            int col = wv * 32 + t * 16 + l15;
            short8 b = *(const short8*)(w2t + (size_t)col * HID_DIM + kb * 32 + q * 8);
            acc[t] = __builtin_amdgcn_mfma_f32_16x16x32_bf16(a, b, acc[t], 0, 0, 0);
        }
    }
#pragma unroll
    for (int t = 0; t < 2; ++t) {
        int col = wv * 32 + t * 16 + l15;
#pragma unroll
        for (int r = 0; r < 4; ++r) {
            int row = row0 + q * 4 + r;
            h2b[(size_t)row * OUT_DIM + col] = f2b(acc[t][r]);
        }
    }
}

// ---------------- gather2: out = Ahat * h2 + b2 (bf16 in, fp32 out) ----------------

__global__ __launch_bounds__(256) void gather2_kernel(const int* __restrict__ cnt,
                                                      const int* __restrict__ bucket,
                                                      const float* __restrict__ dinv,
                                                      const ushort* __restrict__ h2b,
                                                      const float* __restrict__ b2,
                                                      float* __restrict__ out) {
    const int w = blockIdx.x * 4 + (threadIdx.x >> 6);
    const int lane = threadIdx.x & 63;
    const int n = cnt[w];
    const float dd = dinv[w];
    int sv = 0; float nv = 0.f;
    if (lane < n) { sv = bucket[w * BUCKET_CAP + lane]; nv = dinv[sv] * dd; }

    float2 bb = ((const float2*)b2)[lane];
    float2 self = u2f2(((const unsigned*)(h2b + (size_t)w * OUT_DIM))[lane]);
    float sd = dd * dd;
    float2 acc[8];
    acc[0] = {self.x * sd + bb.x, self.y * sd + bb.y};
#pragma unroll
    for (int j = 1; j < 8; ++j) acc[j] = {0.f, 0.f};

    const int nr = (n + 7) & ~7;
    for (int i = 0; i < nr; i += 8) {
        int s[8]; float nm[8]; unsigned u[8];
#pragma unroll
        for (int j = 0; j < 8; ++j) { s[j] = __shfl(sv, i + j); nm[j] = __shfl(nv, i + j); }
#pragma unroll
        for (int j = 0; j < 8; ++j) u[j] = ((const unsigned*)(h2b + (size_t)s[j] * OUT_DIM))[lane];
#pragma unroll
        for (int j = 0; j < 8; ++j) fma2(acc[j], u2f2(u[j]), nm[j]);
    }
#pragma unroll
    for (int j = 1; j < 8; ++j) { acc[0].x += acc[j].x; acc[0].y += acc[j].y; }
    ((float2*)(out + (size_t)w * OUT_DIM))[lane] = acc[0];
}

extern "C" void kernel_launch(void* const* d_in, const int* in_sizes, int n_in,
                              void* d_out, int out_size, void* d_ws, size_t ws_size,
                              hipStream_t stream) {
    const float* x  = (const float*)d_in[0];
    const int*   ei = (const int*)d_in[1];
    const float* W1 = (const float*)d_in[2];
    const float* b1 = (const float*)d_in[3];
    const float* W2 = (const float*)d_in[4];
    const float* b2 = (const float*)d_in[5];
    float* out = (float*)d_out;

    const int* src = ei;             // edge_index[0]
    const int* dst = ei + N_EDGES;   // edge_index[1]

    // workspace layout (bytes):
    //  bincnt2 : [0, 100096)                int[782*32]
    //  cnt     : [100096, 300096)           int[50000]
    //  dinv    : [300096, 500096)           float[50000]
    //  bucket  : [500096, 13300096)         int[50000*64]
    //  binbuf  : [13300096, 22909312)       int[782*32*96]
    //  xb      : [22909312, 35709312)       bf16[50000*128]
    //  aggxb   : [35709312, 48509312)       bf16[50000*128]
    //  w1t     : [48509312, 48574848)       bf16[256*128]
    //  w2t     : [48574848, 48640384)       bf16[128*256]
    //  Hb      : [48640384, 74240384)       bf16[50000*256]
    //  h2b     : [74240384, 87040384)       bf16[50000*128]
    char* ws = (char*)d_ws;
    int*    bincnt2 = (int*)(ws);
    int*    cnt     = (int*)(ws + 100096);
    float*  dinv    = (float*)(ws + 300096);
    int*    bucket  = (int*)(ws + 500096);
    int*    binbuf  = (int*)(ws + 13300096);
    ushort* xb      = (ushort*)(ws + 22909312);
    ushort* aggxb   = (ushort*)(ws + 35709312);
    ushort* w1t     = (ushort*)(ws + 48509312);
    ushort* w2t     = (ushort*)(ws + 48574848);
    ushort* Hb      = (ushort*)(ws + 48640384);
    ushort* h2b     = (ushort*)(ws + 74240384);

    // dtype prep (conv_x also zeroes bincnt2) + graph build
    conv_x_kernel<<<(N_NODES * IN_DIM / 4) / 256, 256, 0, stream>>>(x, xb, bincnt2);
    conv_w_kernel<<<65536 / 256, 256, 0, stream>>>(W1, W2, w1t, w2t);
    binpass1_kernel<<<N_EDGES / 256, 256, 0, stream>>>(src, dst, bincnt2, binbuf);
    binpass2_kernel<<<NBINS, 256, 0, stream>>>(bincnt2, binbuf, cnt, dinv, bucket);

    // layer 1 reordered: aggregate x first, then transform (relu+b1 fused in epilogue)
    gather0_kernel<<<N_NODES / 4, 256, 0, stream>>>(cnt, bucket, dinv, xb, aggxb);
    gemm1_mfma<<<N_NODES / 16, 256, 0, stream>>>(aggxb, w1t, b1, Hb);

    // layer 2: transform then aggregate (self-loop + b2 fused into gather2)
    gemm2_mfma<<<N_NODES / 16, 256, 0, stream>>>(Hb, w2t, h2b);
    gather2_kernel<<<N_NODES / 4, 256, 0, stream>>>(cnt, bucket, dinv, h2b, b2, out);
}

// Round 6
// 243.723 us; speedup vs baseline: 1.7185x; 1.1119x over previous
//
#include <hip/hip_runtime.h>

#define N_NODES 50000
#define N_EDGES 800000
#define IN_DIM  128
#define HID_DIM 256
#define OUT_DIM 128
#define BUCKET_CAP 64    // in-degree ~ Poisson(16); P(deg>64) ~ 2e-18 over 50k nodes
#define NCOARSE 196      // ceil(50000/256) coarse bins of 256 dst nodes
#define COARSE_CAP 4800  // Poisson(4082) + 11 sigma
#define CHUNK 4000       // edges per binpass1 block
#define NBLK1 200        // 200 * 4000 = 800000

typedef __attribute__((ext_vector_type(8))) short short8;
typedef __attribute__((ext_vector_type(4))) float f32x4;

// ---- bf16 helpers (RNE) ----
__device__ inline ushort f2b(float f) {
    union { float f; unsigned u; } v; v.f = f;
    return (ushort)((v.u + 0x7FFFu + ((v.u >> 16) & 1u)) >> 16);
}
__device__ inline float b2f(ushort h) {
    union { unsigned u; float f; } v; v.u = ((unsigned)h) << 16;
    return v.f;
}
__device__ inline float2 u2f2(unsigned u) {
    float2 r; r.x = b2f((ushort)(u & 0xFFFFu)); r.y = b2f((ushort)(u >> 16)); return r;
}
__device__ inline void fma2(float2& a, const float2 v, float n) {
    a.x += v.x * n; a.y += v.y * n;
}

// ---------------- fp32 -> bf16 conversion (+ zero bincnt, fused) ----------------

__global__ void conv_x_kernel(const float* __restrict__ x, ushort* __restrict__ xb,
                              int* __restrict__ bincnt) {
    int i = blockIdx.x * blockDim.x + threadIdx.x;  // 1.6M threads
    if (i < NCOARSE) bincnt[i] = 0;
    float4 v = ((const float4*)x)[i];
    ushort4 o; o.x = f2b(v.x); o.y = f2b(v.y); o.z = f2b(v.z); o.w = f2b(v.w);
    ((ushort4*)xb)[i] = o;
}

// W1 [128x256] -> w1t [256x128] (bf16, transposed); W2 [256x128] -> w2t [128x256]
__global__ void conv_w_kernel(const float* __restrict__ W1, const float* __restrict__ W2,
                              ushort* __restrict__ w1t, ushort* __restrict__ w2t) {
    int i = blockIdx.x * blockDim.x + threadIdx.x;  // 65536 total
    if (i < 32768) {
        int n = i >> 7, k = i & 127;
        w1t[i] = f2b(W1[k * HID_DIM + n]);
    } else {
        int j = i - 32768;
        int n = j >> 8, k = j & 255;
        w2t[j] = f2b(W2[k * OUT_DIM + n]);
    }
}

// ---------------- graph build: block-aggregated binned bucket fill ----------------
// pass 1: per-block LDS histogram over coarse bins (dst>>8), ONE global atomic
// per (block,bin) to reserve a window, then grouped writes into the window.
// Global atomics: 800k -> 39.2k; writes land in contiguous ~80B windows.

__global__ __launch_bounds__(256) void binpass1_kernel(const int* __restrict__ src,
                                                       const int* __restrict__ dst,
                                                       int* __restrict__ bincnt,
                                                       int* __restrict__ binbuf) {
    __shared__ int vals[CHUNK];           // 16 KB: (src<<8)|(dst&255)
    __shared__ ushort lpos[CHUNK];        // 8 KB: order within (block,bin)
    __shared__ unsigned char lbin[CHUNK]; // 4 KB: coarse bin id
    __shared__ int hist[NCOARSE];
    __shared__ int base[NCOARSE];
    const int t = threadIdx.x;
    const int e0 = blockIdx.x * CHUNK;
    for (int i = t; i < NCOARSE; i += 256) hist[i] = 0;
    __syncthreads();
    for (int i = t; i < CHUNK; i += 256) {
        int s = src[e0 + i], d = dst[e0 + i];
        int b = d >> 8;
        vals[i] = (s << 8) | (d & 255);
        lbin[i] = (unsigned char)b;
        lpos[i] = (ushort)atomicAdd(&hist[b], 1);
    }
    __syncthreads();
    for (int i = t; i < NCOARSE; i += 256) base[i] = atomicAdd(&bincnt[i], hist[i]);
    __syncthreads();
    for (int i = t; i < CHUNK; i += 256) {
        int b = lbin[i];
        int p = base[b] + lpos[i];
        if (p < COARSE_CAP) binbuf[b * COARSE_CAP + p] = vals[i];
    }
}

// pass 2: one block per coarse bin (256 nodes); build buckets in 64KB LDS via
// LDS atomics, write bucket + cnt + dinv fully coalesced.
__global__ __launch_bounds__(256) void binpass2_kernel(const int* __restrict__ bincnt,
                                                       const int* __restrict__ binbuf,
                                                       int* __restrict__ cnt,
                                                       float* __restrict__ dinv,
                                                       int* __restrict__ bucket) {
    __shared__ int lcnt[256];
    __shared__ int lbuck[256 * BUCKET_CAP];   // 64 KB
    const int bin = blockIdx.x;
    const int t = threadIdx.x;
    lcnt[t] = 0;
    __syncthreads();
    int m = bincnt[bin];
    if (m > COARSE_CAP) m = COARSE_CAP;
    const int* bb = binbuf + (size_t)bin * COARSE_CAP;
    for (int j = t; j < m; j += 256) {
        int v = bb[j];
        int dl = v & 255;
        int pos = atomicAdd(&lcnt[dl], 1);
        if (pos < BUCKET_CAP) lbuck[dl * BUCKET_CAP + pos] = v >> 8;
    }
    __syncthreads();
    const int node0 = bin * 256;
    int node = node0 + t;
    if (node < N_NODES) {
        int c = lcnt[t] > BUCKET_CAP ? BUCKET_CAP : lcnt[t];
        cnt[node] = c;
        dinv[node] = rsqrtf((float)c + 1.0f);
    }
    int nvalid = N_NODES - node0; if (nvalid > 256) nvalid = 256;
    if (nvalid <= 0) return;
    int total4 = (nvalid * BUCKET_CAP) >> 2;     // int4 count
    int4* d4 = (int4*)(bucket + (size_t)node0 * BUCKET_CAP);
    const int4* s4 = (const int4*)lbuck;
    for (int j = t; j < total4; j += 256) d4[j] = s4[j];
}

// ---------------- gather0: aggx = Ahat * x (bf16 in/out, fp32 acc) ----------------
// one wave per dst node; branch-free unroll-8 (pad lanes: sv=0, nv=0)

__global__ __launch_bounds__(256) void gather0_kernel(const int* __restrict__ cnt,
                                                      const int* __restrict__ bucket,
                                                      const float* __restrict__ dinv,
                                                      const ushort* __restrict__ xb,
                                                      ushort* __restrict__ aggxb) {
    const int w = blockIdx.x * 4 + (threadIdx.x >> 6);
    const int lane = threadIdx.x & 63;
    const int n = cnt[w];
    const float dd = dinv[w];
    int sv = 0; float nv = 0.f;
    if (lane < n) { sv = bucket[w * BUCKET_CAP + lane]; nv = dinv[sv] * dd; }

    float2 self = u2f2(((const unsigned*)(xb + (size_t)w * IN_DIM))[lane]);
    float sd = dd * dd;
    float2 acc[8];
    acc[0] = {self.x * sd, self.y * sd};
#pragma unroll
    for (int j = 1; j < 8; ++j) acc[j] = {0.f, 0.f};

    const int nr = (n + 7) & ~7;
    for (int i = 0; i < nr; i += 8) {
        int s[8]; float nm[8]; unsigned u[8];
#pragma unroll
        for (int j = 0; j < 8; ++j) { s[j] = __shfl(sv, i + j); nm[j] = __shfl(nv, i + j); }
#pragma unroll
        for (int j = 0; j < 8; ++j) u[j] = ((const unsigned*)(xb + (size_t)s[j] * IN_DIM))[lane];
#pragma unroll
        for (int j = 0; j < 8; ++j) fma2(acc[j], u2f2(u[j]), nm[j]);
    }
#pragma unroll
    for (int j = 1; j < 8; ++j) { acc[0].x += acc[j].x; acc[0].y += acc[j].y; }
    unsigned o = (unsigned)f2b(acc[0].x) | ((unsigned)f2b(acc[0].y) << 16);
    ((unsigned*)(aggxb + (size_t)w * IN_DIM))[lane] = o;
}

// ---------------- gemm1 (MFMA): Hb = relu(aggx @ W1 + b1), bf16 out ----------------

__global__ __launch_bounds__(256) void gemm1_mfma(const ushort* __restrict__ aggxb,
                                                  const ushort* __restrict__ w1t,
                                                  const float* __restrict__ b1,
                                                  ushort* __restrict__ Hb) {
    const int row0 = blockIdx.x * 16;
    const int wv = threadIdx.x >> 6;
    const int lane = threadIdx.x & 63;
    const int l15 = lane & 15, q = lane >> 4;
    f32x4 acc[4] = {{0.f, 0.f, 0.f, 0.f}, {0.f, 0.f, 0.f, 0.f},
                    {0.f, 0.f, 0.f, 0.f}, {0.f, 0.f, 0.f, 0.f}};
    const ushort* abase = aggxb + (size_t)(row0 + l15) * IN_DIM + q * 8;
#pragma unroll
    for (int kb = 0; kb < 4; ++kb) {
        short8 a = *(const short8*)(abase + kb * 32);
#pragma unroll
        for (int t = 0; t < 4; ++t) {
            int col = wv * 64 + t * 16 + l15;
            short8 b = *(const short8*)(w1t + (size_t)col * IN_DIM + kb * 32 + q * 8);
            acc[t] = __builtin_amdgcn_mfma_f32_16x16x32_bf16(a, b, acc[t], 0, 0, 0);
        }
    }
#pragma unroll
    for (int t = 0; t < 4; ++t) {
        int col = wv * 64 + t * 16 + l15;
        float bias = b1[col];
#pragma unroll
        for (int r = 0; r < 4; ++r) {
            int row = row0 + q * 4 + r;
            float v = acc[t][r] + bias;
            Hb[(size_t)row * HID_DIM + col] = f2b(v > 0.f ? v : 0.f);
        }
    }
}

// ---------------- gemm2 (MFMA): h2b = Hb @ W2, bf16 out ----------------

__global__ __launch_bounds__(256) void gemm2_mfma(const ushort* __restrict__ Hb,
                                                  const ushort* __restrict__ w2t,
                                                  ushort* __restrict__ h2b) {
    const int row0 = blockIdx.x * 16;
    const int wv = threadIdx.x >> 6;
    const int lane = threadIdx.x & 63;
    const int l15 = lane & 15, q = lane >> 4;
    f32x4 acc[2] = {{0.f, 0.f, 0.f, 0.f}, {0.f, 0.f, 0.f, 0.f}};
    const ushort* abase = Hb + (size_t)(row0 + l15) * HID_DIM + q * 8;
#pragma unroll
    for (int kb = 0; kb < 8; ++kb) {
        short8 a = *(const short8*)(abase + kb * 32);
#pragma unroll
        for (int t = 0; t < 2; ++t) {
            int col = wv * 32 + t * 16 + l15;
            short8 b = *(const short8*)(w2t + (size_t)col * HID_DIM + kb * 32 + q * 8);
            acc[t] = __builtin_amdgcn_mfma_f32_16x16x32_bf16(a, b, acc[t], 0, 0, 0);
        }
    }
#pragma unroll
    for (int t = 0; t < 2; ++t) {
        int col = wv * 32 + t * 16 + l15;
#pragma unroll
        for (int r = 0; r < 4; ++r) {
            int row = row0 + q * 4 + r;
            h2b[(size_t)row * OUT_DIM + col] = f2b(acc[t][r]);
        }
    }
}

// ---------------- gather2: out = Ahat * h2 + b2 (bf16 in, fp32 out) ----------------

__global__ __launch_bounds__(256) void gather2_kernel(const int* __restrict__ cnt,
                                                      const int* __restrict__ bucket,
                                                      const float* __restrict__ dinv,
                                                      const ushort* __restrict__ h2b,
                                                      const float* __restrict__ b2,
                                                      float* __restrict__ out) {
    const int w = blockIdx.x * 4 + (threadIdx.x >> 6);
    const int lane = threadIdx.x & 63;
    const int n = cnt[w];
    const float dd = dinv[w];
    int sv = 0; float nv = 0.f;
    if (lane < n) { sv = bucket[w * BUCKET_CAP + lane]; nv = dinv[sv] * dd; }

    float2 bb = ((const float2*)b2)[lane];
    float2 self = u2f2(((const unsigned*)(h2b + (size_t)w * OUT_DIM))[lane]);
    float sd = dd * dd;
    float2 acc[8];
    acc[0] = {self.x * sd + bb.x, self.y * sd + bb.y};
#pragma unroll
    for (int j = 1; j < 8; ++j) acc[j] = {0.f, 0.f};

    const int nr = (n + 7) & ~7;
    for (int i = 0; i < nr; i += 8) {
        int s[8]; float nm[8]; unsigned u[8];
#pragma unroll
        for (int j = 0; j < 8; ++j) { s[j] = __shfl(sv, i + j); nm[j] = __shfl(nv, i + j); }
#pragma unroll
        for (int j = 0; j < 8; ++j) u[j] = ((const unsigned*)(h2b + (size_t)s[j] * OUT_DIM))[lane];
#pragma unroll
        for (int j = 0; j < 8; ++j) fma2(acc[j], u2f2(u[j]), nm[j]);
    }
#pragma unroll
    for (int j = 1; j < 8; ++j) { acc[0].x += acc[j].x; acc[0].y += acc[j].y; }
    ((float2*)(out + (size_t)w * OUT_DIM))[lane] = acc[0];
}

extern "C" void kernel_launch(void* const* d_in, const int* in_sizes, int n_in,
                              void* d_out, int out_size, void* d_ws, size_t ws_size,
                              hipStream_t stream) {
    const float* x  = (const float*)d_in[0];
    const int*   ei = (const int*)d_in[1];
    const float* W1 = (const float*)d_in[2];
    const float* b1 = (const float*)d_in[3];
    const float* W2 = (const float*)d_in[4];
    const float* b2 = (const float*)d_in[5];
    float* out = (float*)d_out;

    const int* src = ei;             // edge_index[0]
    const int* dst = ei + N_EDGES;   // edge_index[1]

    // workspace layout (bytes):
    //  bincnt : [0, 1024)                   int[196]
    //  cnt    : [1024, 201024)              int[50000]
    //  dinv   : [201024, 401024)            float[50000]
    //  bucket : [401024, 13201024)          int[50000*64]
    //  binbuf : [13201024, 16964224)        int[196*4800]
    //  xb     : [16964224, 29764224)        bf16[50000*128]
    //  aggxb  : [29764224, 42564224)        bf16[50000*128]
    //  w1t    : [42564224, 42629760)        bf16[256*128]
    //  w2t    : [42629760, 42695296)        bf16[128*256]
    //  Hb     : [42695296, 68295296)        bf16[50000*256]
    //  h2b    : [68295296, 81095296)        bf16[50000*128]
    char* ws = (char*)d_ws;
    int*    bincnt = (int*)(ws);
    int*    cnt    = (int*)(ws + 1024);
    float*  dinv   = (float*)(ws + 201024);
    int*    bucket = (int*)(ws + 401024);
    int*    binbuf = (int*)(ws + 13201024);
    ushort* xb     = (ushort*)(ws + 16964224);
    ushort* aggxb  = (ushort*)(ws + 29764224);
    ushort* w1t    = (ushort*)(ws + 42564224);
    ushort* w2t    = (ushort*)(ws + 42629760);
    ushort* Hb     = (ushort*)(ws + 42695296);
    ushort* h2b    = (ushort*)(ws + 68295296);

    // dtype prep (conv_x also zeroes bincnt) + graph build
    conv_x_kernel<<<(N_NODES * IN_DIM / 4) / 256, 256, 0, stream>>>(x, xb, bincnt);
    conv_w_kernel<<<65536 / 256, 256, 0, stream>>>(W1, W2, w1t, w2t);
    binpass1_kernel<<<NBLK1, 256, 0, stream>>>(src, dst, bincnt, binbuf);
    binpass2_kernel<<<NCOARSE, 256, 0, stream>>>(bincnt, binbuf, cnt, dinv, bucket);

    // layer 1 reordered: aggregate x first, then transform (relu+b1 fused in epilogue)
    gather0_kernel<<<N_NODES / 4, 256, 0, stream>>>(cnt, bucket, dinv, xb, aggxb);
    gemm1_mfma<<<N_NODES / 16, 256, 0, stream>>>(aggxb, w1t, b1, Hb);

    // layer 2: transform then aggregate (self-loop + b2 fused into gather2)
    gemm2_mfma<<<N_NODES / 16, 256, 0, stream>>>(Hb, w2t, h2b);
    gather2_kernel<<<N_NODES / 4, 256, 0, stream>>>(cnt, bucket, dinv, h2b, b2, out);
}